// Round 3
// baseline (813.998 us; speedup 1.0000x reference)
//
#include <hip/hip_runtime.h>

// StressTestModel: B=4 S=1024 V=32000 D=128 H=8 dh=16 N=128
// Pipeline: prol(prep) -> scan(+xposeT, +cast on idle CUs) -> qk -> attn_z
//           -> attn_w(+mirror zero) -> ctx(fused 2-GEMM + X-add) -> theta
//           -> WriWi gemm(+silu) -> out gemm(nt)

#define DEV static __device__ __forceinline__

typedef __attribute__((ext_vector_type(8))) short short8;
typedef __attribute__((ext_vector_type(4))) float f32x4;

#define INV2PI 0.15915494309189535f
#define INVPI  0.3183098861837907f
#define PHI    1.6180339887498949f
#define SQRT2  1.4142135623730951f
#define SS2    0.25503471060f         /* log2(e)/sqrt(32) */

DEV unsigned short f2bf(float x){
  unsigned u = __float_as_uint(x);
  u += 0x7fff + ((u >> 16) & 1);      // RNE
  return (unsigned short)(u >> 16);
}
DEV float fract1(float x){ return __builtin_amdgcn_fractf(x); }
DEV float sin2pi(float f){ return __builtin_amdgcn_sinf(f); }   // v_sin: revolutions
DEV float cos2pi(float f){ return __builtin_amdgcn_cosf(f); }
DEV float rcpf_(float x){ return __builtin_amdgcn_rcpf(x); }

DEV void cp16(const float* g, float* l){
  __builtin_amdgcn_global_load_lds(
      (const __attribute__((address_space(1))) unsigned*)g,
      (__attribute__((address_space(3))) unsigned*)l, 16, 0, 0);
}

// ---------------- prologue: embedding gather -> scan coefficients ----------------
// P[(b*1024+t)*128+d] = (a2, c2):  u' = sin2pi(fract(u*a2 + c2)), s = sqrt2*u'
__global__ __launch_bounds__(256) void k_prol(
    const int* __restrict__ ids, const float* __restrict__ emb,
    float* __restrict__ P){
  int bt = blockIdx.x*2 + (threadIdx.x >> 7);   // b*1024 + t
  int t  = bt & 1023;
  int d  = threadIdx.x & 127;
  int id = ids[bt];
  float w  = emb[id*256 + d];
  float bb = emb[id*256 + 128 + d];
  // sin+cos fold: s = sqrt2*sin2pi(rev + 1/8); fold sqrt2 into a, 1/8 into c
  float a2 = SQRT2 * INV2PI * rcpf_(1.f + fabsf(w));
  float c2 = (bb + (float)t * PHI) * INVPI + 0.125f;
  ((float2*)P)[bt*128 + d] = make_float2(a2, c2);
}

// ---------------- scan (blocks 0-3) + weight casts (blocks 4+, idle-CU work) ----
// scan: u_t = sin2pi(fract(u_{t-1}*a2 + c2)), s = sqrt2*u; also emits X^T bf16
__global__ __launch_bounds__(128) void k_scan(const float* __restrict__ P,
    float* __restrict__ X, unsigned short* __restrict__ XT,
    const float* __restrict__ Wctx, const float* __restrict__ Wres,
    const float* __restrict__ Bres, const float* __restrict__ Wreal,
    const float* __restrict__ Wimag, const float* __restrict__ Wout,
    unsigned short* __restrict__ Woutb, unsigned short* __restrict__ Wctxb,
    unsigned short* __restrict__ WriTb, float* __restrict__ raT,
    float* __restrict__ rcT){
  __shared__ float buf[2][32*256];   // 64 KiB: double-buffered 32-step chunks
  int bx = blockIdx.x;
  int tid = threadIdx.x;
  if (bx >= 4){
    int bxc = bx - 4;
    if (bxc < 2000){
      // Wout cast: 16-deep register batch for MLP at 2-blocks/CU occupancy
      const float* src = Wout + bxc*2048 + tid;
      float r[16];
      #pragma unroll
      for (int it = 0; it < 16; it++) r[it] = src[it*128];
      unsigned short* dst = Woutb + bxc*2048 + tid;
      #pragma unroll
      for (int it = 0; it < 16; it++) dst[it*128] = f2bf(r[it]);
      return;
    }
    int i = (bxc - 2000)*128 + tid;   // [0, 65536)
    if (i < 16384){ Wctxb[i] = f2bf(Wctx[i]); return; }
    i -= 16384;
    if (i < 32768){
      int d = i >> 8, kk = i & 255;
      WriTb[i] = f2bf(kk < 128 ? Wreal[d*128 + kk] : Wimag[d*128 + kk - 128]);
      return;
    }
    i -= 32768;
    int d = i >> 7, n = i & 127;
    raT[i] = INV2PI * rcpf_(1.f + fabsf(Wres[n*128 + d]));  // raT[d][n]
    rcT[i] = Bres[n*128 + d] * INV2PI;                      // rcT[d][n]
    return;
  }
  int b  = bx;
  int wv = tid >> 6, ln = tid & 63;
  const float* Pb = P + (size_t)b * 1024 * 256;
  for (int i = 0; i < 16; i++){
    int o = (i*2 + wv) * 256;
    cp16(Pb + o + ln*4, &buf[0][o]);
  }
  __syncthreads();
  float u = 0.f;   // u = s/sqrt2; first step rev = c2 matches s0=0
  float* Xb = X + (size_t)b * 1024 * 128;
  unsigned short* XTb = XT + (size_t)(b*128 + tid) * 1024;
  for (int c = 0; c < 32; c++){
    int cur = c & 1;
    if (c + 1 < 32){
      const float* Pn = Pb + (size_t)(c+1) * 8192;
      float* lb = &buf[cur ^ 1][0];
      for (int i = 0; i < 16; i++){
        int o = (i*2 + wv) * 256;
        cp16(Pn + o + ln*4, lb + o);
      }
    }
    const float* bc = &buf[cur][0];
    unsigned pk[16];
    #pragma unroll 8
    for (int t = 0; t < 32; t++){
      float a  = bc[t*256 + tid*2];
      float cc = bc[t*256 + tid*2 + 1];
      float f = fract1(fmaf(u, a, cc));   // chain: fmaf -> fract -> sin
      u = sin2pi(f);
      float s = u * SQRT2;                // off-chain
      Xb[(c*32 + t)*128 + tid] = s;
      unsigned short h = f2bf(s);
      if (t & 1) pk[t>>1] |= (unsigned)h << 16;
      else       pk[t>>1]  = (unsigned)h;
    }
    uint4* dst = (uint4*)(XTb + c*32);
    #pragma unroll
    for (int i = 0; i < 4; i++)
      dst[i] = make_uint4(pk[i*4+0], pk[i*4+1], pk[i*4+2], pk[i*4+3]);
    __syncthreads();
  }
}

// ---------------- q/k build: q[b][t][h][0..15]=cos, [16..31]=sin ----------------
__global__ __launch_bounds__(128) void k_qk(const float* __restrict__ X,
    const float* __restrict__ wq, const float* __restrict__ bq,
    const float* __restrict__ wk, const float* __restrict__ bk,
    unsigned short* __restrict__ q, unsigned short* __restrict__ k){
  int bt = blockIdx.x;
  int t = bt & 1023;
  int tid = threadIdx.x;            // h*16 + c
  float x = X[(size_t)bt*128 + tid];
  int h = tid >> 4, c = tid & 15;
  size_t base = (size_t)bt*256 + h*32 + c;
  float aq = rcpf_(1.f + fabsf(wq[tid]));
  float fq = fract1(fmaf(x, aq, bq[tid] + (float)t * PHI) * INV2PI);
  q[base]      = f2bf(cos2pi(fq));
  q[base + 16] = f2bf(sin2pi(fq));
  float ak = rcpf_(1.f + fabsf(wk[tid]));
  float fk = fract1(fmaf(x, ak, bk[tid]) * INV2PI);
  k[base]      = f2bf(cos2pi(fk));
  k[base + 16] = f2bf(sin2pi(fk));
}

// ---------------- attention pass 1: Z[b][h][i] = sum_{j<i} exp(score) ----------------
// scores bounded by 2.83 -> no max subtraction needed
__global__ __launch_bounds__(256) void k_attn_z(const unsigned short* __restrict__ q,
    const unsigned short* __restrict__ k, float* __restrict__ Z){
  int blk = blockIdx.x;             // b*128 + h*16 + it
  int it = blk & 15, h = (blk >> 4) & 7, b = blk >> 7;
  int tid = threadIdx.x, w = tid >> 6, ln = tid & 63;
  int ib = it*64 + w*16;
  short8 qa = *(const short8*)(q + ((size_t)(b*1024 + ib + (ln & 15))*8 + h)*32 + (ln >> 4)*8);
  const unsigned short* kb = k + ((size_t)(b*1024 + (ln & 15))*8 + h)*32 + (ln >> 4)*8;
  float z0 = 0.f, z1 = 0.f, z2 = 0.f, z3 = 0.f;
  int irow = ib + (ln >> 4)*4;
  int jcol = ln & 15;
  for (int jt = 0; jt <= (ib >> 4); jt++){
    short8 kf = *(const short8*)(kb + (size_t)jt*16*256);
    f32x4 c = {0.f, 0.f, 0.f, 0.f};
    c = __builtin_amdgcn_mfma_f32_16x16x32_bf16(qa, kf, c, 0, 0, 0);
    int j = jt*16 + jcol;
    if (j < irow + 0) z0 += exp2f(c[0]*SS2);
    if (j < irow + 1) z1 += exp2f(c[1]*SS2);
    if (j < irow + 2) z2 += exp2f(c[2]*SS2);
    if (j < irow + 3) z3 += exp2f(c[3]*SS2);
  }
  #pragma unroll
  for (int m = 1; m < 16; m <<= 1){
    z0 += __shfl_xor(z0, m, 64); z1 += __shfl_xor(z1, m, 64);
    z2 += __shfl_xor(z2, m, 64); z3 += __shfl_xor(z3, m, 64);
  }
  if ((ln & 15) == 0){
    float* zp = Z + (size_t)(b*8 + h)*1024 + irow;
    zp[0] = z0; zp[1] = z1; zp[2] = z2; zp[3] = z3;
  }
}

// ---------------- attention pass 2: Wsum[b][i][j] = sum_h exp(score)/Z ----------------
// off-diagonal blocks also zero their mirrored upper-triangle tile (replaces memset)
__global__ __launch_bounds__(256) void k_attn_w(const unsigned short* __restrict__ q,
    const unsigned short* __restrict__ k, const float* __restrict__ Z,
    unsigned short* __restrict__ W){
  __shared__ float invZ[8][64];
  int b = blockIdx.x / 136, tr = blockIdx.x % 136;
  int it = 0; while ((it+1)*(it+2)/2 <= tr) it++;
  int jt = tr - it*(it+1)/2;
  int ib = it*64, jb = jt*64;
  int tid = threadIdx.x;
  if (it != jt){
    // zero mirrored tile: rows [jb,jb+64) cols [ib,ib+64)  (strictly upper)
    uint4 z4 = make_uint4(0u, 0u, 0u, 0u);
    int idx = tid*2;
    #pragma unroll
    for (int s = 0; s < 2; s++, idx++){
      int row = idx >> 3, c4 = idx & 7;
      *(uint4*)(W + (size_t)(b*1024 + jb + row)*1024 + ib + c4*8) = z4;
    }
  }
  for (int i = tid; i < 512; i += 256){
    int hh = i >> 6, rr = i & 63;
    float zz = Z[(size_t)(b*8 + hh)*1024 + ib + rr];
    invZ[hh][rr] = zz > 0.f ? rcpf_(zz) : 0.f;
  }
  __syncthreads();
  int w = tid >> 6, ln = tid & 63;
  int iw = ib + w*16;
  int rloc = w*16 + (ln >> 4)*4;
  int irow = iw + (ln >> 4)*4;
  int jcol = ln & 15;
  float acc[4][4] = {};
  for (int h = 0; h < 8; h++){
    short8 qa = *(const short8*)(q + ((size_t)(b*1024 + iw + (ln & 15))*8 + h)*32 + (ln >> 4)*8);
    float iz0 = invZ[h][rloc+0], iz1 = invZ[h][rloc+1];
    float iz2 = invZ[h][rloc+2], iz3 = invZ[h][rloc+3];
    for (int jtt = 0; jtt < 4; jtt++){
      short8 kf = *(const short8*)(k + ((size_t)(b*1024 + jb + jtt*16 + (ln & 15))*8 + h)*32 + (ln >> 4)*8);
      f32x4 c = {0.f, 0.f, 0.f, 0.f};
      c = __builtin_amdgcn_mfma_f32_16x16x32_bf16(qa, kf, c, 0, 0, 0);
      int j = jb + jtt*16 + jcol;
      if (j < irow + 0) acc[jtt][0] += exp2f(c[0]*SS2)*iz0;
      if (j < irow + 1) acc[jtt][1] += exp2f(c[1]*SS2)*iz1;
      if (j < irow + 2) acc[jtt][2] += exp2f(c[2]*SS2)*iz2;
      if (j < irow + 3) acc[jtt][3] += exp2f(c[3]*SS2)*iz3;
    }
  }
  #pragma unroll
  for (int jtt = 0; jtt < 4; jtt++)
    #pragma unroll
    for (int r = 0; r < 4; r++)
      W[(size_t)(b*1024 + irow + r)*1024 + jb + jtt*16 + jcol] = f2bf(acc[jtt][r]);
}

// ---------------- fused: tmp = Wsum@X (causal), xout = X + bf16(tmp)@Wctx^T -------
// grid (8,1,4); each block owns a complete 128x128 tmp tile (N=128), routes it
// through LDS (stride 136 -> 16B-aligned b128 reads), then K=128 second GEMM.
__global__ __launch_bounds__(256) void k_ctx(const unsigned short* __restrict__ Wsum,
    const unsigned short* __restrict__ XT, const unsigned short* __restrict__ Wctxb,
    const float* __restrict__ X, float* __restrict__ xout){
  __shared__ unsigned short tile[128][136];
  int b = blockIdx.z;
  const unsigned short* A = Wsum + (long)b*1024*1024;
  const unsigned short* Bm = XT + (long)b*128*1024;
  int tid = threadIdx.x, w = tid >> 6, ln = tid & 63;
  int mq = (w & 1)*64, nq = (w >> 1)*64;
  int m0 = blockIdx.x*128 + mq;
  int kmax = (blockIdx.x + 1)*128;
  f32x4 acc[4][4];
  #pragma unroll
  for (int i = 0; i < 4; i++)
    #pragma unroll
    for (int j = 0; j < 4; j++) acc[i][j] = (f32x4){0.f, 0.f, 0.f, 0.f};
  const unsigned short* Ap = A + (long)(m0 + (ln & 15))*1024 + (ln >> 4)*8;
  const unsigned short* Bp = Bm + (long)(nq + (ln & 15))*1024 + (ln >> 4)*8;
  for (int kb = 0; kb < kmax; kb += 32){
    short8 af[4], bf[4];
    #pragma unroll
    for (int i = 0; i < 4; i++) af[i] = *(const short8*)(Ap + (long)i*16*1024 + kb);
    #pragma unroll
    for (int i = 0; i < 4; i++) bf[i] = *(const short8*)(Bp + (long)i*16*1024 + kb);
    #pragma unroll
    for (int i = 0; i < 4; i++)
      #pragma unroll
      for (int j = 0; j < 4; j++)
        acc[i][j] = __builtin_amdgcn_mfma_f32_16x16x32_bf16(af[i], bf[j], acc[i][j], 0, 0, 0);
  }
  int r0 = (ln >> 4)*4, jc = ln & 15;
  #pragma unroll
  for (int i = 0; i < 4; i++)
    #pragma unroll
    for (int j = 0; j < 4; j++)
      #pragma unroll
      for (int r = 0; r < 4; r++)
        tile[mq + i*16 + r0 + r][nq + j*16 + jc] = f2bf(acc[i][j][r]);
  __syncthreads();
  // phase 2: quadrant (mq, nq) of tile_bf16 @ Wctxb^T, K=128
  f32x4 acc2[4][4];
  #pragma unroll
  for (int i = 0; i < 4; i++)
    #pragma unroll
    for (int j = 0; j < 4; j++) acc2[i][j] = (f32x4){0.f, 0.f, 0.f, 0.f};
  for (int kb = 0; kb < 128; kb += 32){
    short8 af[4], bf[4];
    #pragma unroll
    for (int i = 0; i < 4; i++)
      af[i] = *(const short8*)&tile[mq + i*16 + (ln & 15)][(ln >> 4)*8 + kb];
    #pragma unroll
    for (int j = 0; j < 4; j++)
      bf[j] = *(const short8*)(Wctxb + (long)(nq + j*16 + (ln & 15))*128 + (ln >> 4)*8 + kb);
    #pragma unroll
    for (int i = 0; i < 4; i++)
      #pragma unroll
      for (int j = 0; j < 4; j++)
        acc2[i][j] = __builtin_amdgcn_mfma_f32_16x16x32_bf16(af[i], bf[j], acc2[i][j], 0, 0, 0);
  }
  // epilogue: xout = X + ctx2  (absorbs k_theta's add)
  #pragma unroll
  for (int i = 0; i < 4; i++)
    #pragma unroll
    for (int j = 0; j < 4; j++)
      #pragma unroll
      for (int r = 0; r < 4; r++){
        long idx = (long)(b*1024 + blockIdx.x*128 + mq + i*16 + r0 + r)*128 + nq + j*16 + jc;
        xout[idx] = X[idx] + acc2[i][j][r];
      }
}

// ---------------- cs/ss = sum_d cos/sin(theta), from xout ----------------
__global__ __launch_bounds__(128) void k_theta(const float* __restrict__ xout,
    const float* __restrict__ raT, const float* __restrict__ rcT,
    unsigned short* __restrict__ A7){
  __shared__ float xs[8][128];
  int b = blockIdx.x >> 7, sc = blockIdx.x & 127;
  int s0 = sc*8;
  int n = threadIdx.x;
  #pragma unroll
  for (int s = 0; s < 8; s++){
    size_t idx = (size_t)(b*1024 + s0 + s)*128 + n;
    xs[s][n] = xout[idx];
  }
  __syncthreads();
  float tp[8];
  #pragma unroll
  for (int s = 0; s < 8; s++) tp[s] = (float)(s0 + s) * (float)(PHI * INV2PI);
  float cs[8] = {0,0,0,0,0,0,0,0}, ss[8] = {0,0,0,0,0,0,0,0};
  for (int d = 0; d < 128; d++){
    float a  = raT[d*128 + n];
    float c0 = rcT[d*128 + n];
    #pragma unroll
    for (int s = 0; s < 8; s++){
      float f = fract1(fmaf(xs[s][d], a, c0) + tp[s]);
      cs[s] += cos2pi(f);
      ss[s] += sin2pi(f);
    }
  }
  #pragma unroll
  for (int s = 0; s < 8; s++){
    size_t row = (size_t)(b*1024 + s0 + s);
    A7[row*256 + n]       = f2bf(cs[s]);
    A7[row*256 + 128 + n] = f2bf(ss[s]);
  }
}

// ---------------- generic bf16 MFMA GEMM: C[m][n] = sum_k A[m][k]*B[n][k] ----------------
// obf: 0 = f32 store, 1 = bf16 store, 2 = bf16(Xadd + silu(acc)), 3 = f32 nontemporal
__global__ __launch_bounds__(256) void k_gemm(const unsigned short* __restrict__ A,
    const unsigned short* __restrict__ B, void* __restrict__ Cv,
    int K, int lda, int ldb, int ldc,
    long Abat, long Bbat, long Cbat, int causal, int obf,
    const float* __restrict__ Xadd){
  int bz = blockIdx.z;
  A += (long)bz * Abat; B += (long)bz * Bbat;
  int tid = threadIdx.x, w = tid >> 6, ln = tid & 63;
  int m0 = blockIdx.x*128 + (w & 1)*64;
  int n0 = blockIdx.y*128 + (w >> 1)*64;
  int kmax = causal ? (blockIdx.x + 1)*128 : K;
  if (kmax > K) kmax = K;
  f32x4 acc[4][4];
  #pragma unroll
  for (int i = 0; i < 4; i++)
    #pragma unroll
    for (int j = 0; j < 4; j++) acc[i][j] = (f32x4){0.f, 0.f, 0.f, 0.f};
  const unsigned short* Ap = A + (long)(m0 + (ln & 15))*lda + (ln >> 4)*8;
  const unsigned short* Bp = B + (long)(n0 + (ln & 15))*ldb + (ln >> 4)*8;
  for (int kb = 0; kb < kmax; kb += 32){
    short8 af[4], bf[4];
    #pragma unroll
    for (int i = 0; i < 4; i++) af[i] = *(const short8*)(Ap + (long)i*16*lda + kb);
    #pragma unroll
    for (int i = 0; i < 4; i++) bf[i] = *(const short8*)(Bp + (long)i*16*ldb + kb);
    #pragma unroll
    for (int i = 0; i < 4; i++)
      #pragma unroll
      for (int j = 0; j < 4; j++)
        acc[i][j] = __builtin_amdgcn_mfma_f32_16x16x32_bf16(af[i], bf[j], acc[i][j], 0, 0, 0);
  }
  int r0 = (ln >> 4)*4, jc = ln & 15;
  if (obf == 1){
    unsigned short* C = (unsigned short*)Cv + (long)bz * Cbat;
    #pragma unroll
    for (int i = 0; i < 4; i++)
      #pragma unroll
      for (int j = 0; j < 4; j++)
        #pragma unroll
        for (int r = 0; r < 4; r++)
          C[(long)(m0 + i*16 + r0 + r)*ldc + n0 + j*16 + jc] = f2bf(acc[i][j][r]);
  } else if (obf == 2){
    // epilogue-fused silu: C = bf16(Xadd + acc*sigmoid(acc))
    unsigned short* C = (unsigned short*)Cv;
    #pragma unroll
    for (int i = 0; i < 4; i++)
      #pragma unroll
      for (int j = 0; j < 4; j++)
        #pragma unroll
        for (int r = 0; r < 4; r++){
          long idx = (long)(m0 + i*16 + r0 + r)*ldc + n0 + j*16 + jc;
          float uu = acc[i][j][r];
          float sig = rcpf_(1.f + __expf(-uu));
          C[idx] = f2bf(Xadd[idx] + uu*sig);
        }
  } else if (obf == 3){
    // streaming f32 output (the 524 MB tail) -- keep it out of L2
    float* C = (float*)Cv + (long)bz * Cbat;
    #pragma unroll
    for (int i = 0; i < 4; i++)
      #pragma unroll
      for (int j = 0; j < 4; j++)
        #pragma unroll
        for (int r = 0; r < 4; r++)
          __builtin_nontemporal_store(acc[i][j][r],
              C + (long)(m0 + i*16 + r0 + r)*ldc + n0 + j*16 + jc);
  } else {
    float* C = (float*)Cv + (long)bz * Cbat;
    #pragma unroll
    for (int i = 0; i < 4; i++)
      #pragma unroll
      for (int j = 0; j < 4; j++)
        #pragma unroll
        for (int r = 0; r < 4; r++)
          C[(long)(m0 + i*16 + r0 + r)*ldc + n0 + j*16 + jc] = acc[i][j][r];
  }
}

extern "C" void kernel_launch(void* const* d_in, const int* in_sizes, int n_in,
                              void* d_out, int out_size, void* d_ws, size_t ws_size,
                              hipStream_t stream){
  const int*   ids  = (const int*)  d_in[0];
  const float* emb  = (const float*)d_in[1];
  const float* wq   = (const float*)d_in[2];
  const float* bq   = (const float*)d_in[3];
  const float* wk   = (const float*)d_in[4];
  const float* bk   = (const float*)d_in[5];
  const float* Wctx = (const float*)d_in[6];
  const float* Wres = (const float*)d_in[7];
  const float* Bres = (const float*)d_in[8];
  const float* Wreal= (const float*)d_in[9];
  const float* Wimag= (const float*)d_in[10];
  const float* Wout = (const float*)d_in[11];

  char* p = (char*)d_ws;
  auto alloc = [&](size_t bytes) -> void* {
    void* r = (void*)p; p += (bytes + 255) & ~(size_t)255; return r;
  };
  float*          P     = (float*)         alloc(4ull*1024*128*2*4); // (a2,c2) pairs
  float*          X     = (float*)         alloc(4ull*1024*128*4);
  unsigned short* XT    = (unsigned short*)alloc(4ull*128*1024*2);
  unsigned short* q     = (unsigned short*)alloc(4ull*1024*256*2);
  unsigned short* k     = (unsigned short*)alloc(4ull*1024*256*2);
  float*          Z     = (float*)         alloc(4ull*8*1024*4);
  unsigned short* Wsum  = (unsigned short*)alloc(4ull*1024*1024*2);
  float*          xout  = (float*)         alloc(4ull*1024*128*4);
  unsigned short* A7    = (unsigned short*)alloc(4096ull*256*2);
  unsigned short* xb    = (unsigned short*)alloc(4096ull*128*2);
  unsigned short* Woutb = (unsigned short*)alloc(32000ull*128*2);
  unsigned short* Wctxb = (unsigned short*)alloc(128ull*128*2);
  unsigned short* WriTb = (unsigned short*)alloc(128ull*256*2);
  float*          raT   = (float*)         alloc(16384ull*4);
  float*          rcT   = (float*)         alloc(16384ull*4);

  hipLaunchKernelGGL(k_prol,  dim3(2048), dim3(256), 0, stream, ids, emb, P);
  // blocks 0-3: scan; blocks 4-2003: Wout cast (16-deep); 2004-2515: small casts
  hipLaunchKernelGGL(k_scan,  dim3(2516), dim3(128), 0, stream, P, X, XT,
                     Wctx, Wres, Bres, Wreal, Wimag, Wout,
                     Woutb, Wctxb, WriTb, raT, rcT);
  hipLaunchKernelGGL(k_qk,    dim3(4096), dim3(128), 0, stream, X, wq, bq, wk, bk, q, k);
  hipLaunchKernelGGL(k_attn_z,dim3(512),  dim3(256), 0, stream, q, k, Z);
  hipLaunchKernelGGL(k_attn_w,dim3(544),  dim3(256), 0, stream, q, k, Z, Wsum);
  // xout = X + (bf16(Wsum@X) @ Wctx^T)   (two GEMMs fused through LDS)
  hipLaunchKernelGGL(k_ctx,   dim3(8,1,4), dim3(256), 0, stream,
                     Wsum, XT, Wctxb, X, xout);
  hipLaunchKernelGGL(k_theta, dim3(512), dim3(128), 0, stream, xout, raT, rcT, A7);
  // xb = bf16(xout + silu([cs|ss] @ [Wr|Wi]^T))   (silu fused into epilogue)
  hipLaunchKernelGGL(k_gemm,  dim3(32,1,1), dim3(256), 0, stream,
                     A7, WriTb, (void*)xb, 256, 256, 256, 128,
                     0L, 0L, 0L, 0, 2, xout);
  // out = x @ Wout^T  (4096 x 32000 x 128) -- the HBM-write-bound tail, nt stores
  hipLaunchKernelGGL(k_gemm,  dim3(32,250,1), dim3(256), 0, stream,
                     xb, Woutb, d_out, 128, 128, 128, 32000,
                     0L, 0L, 0L, 0, 3, (const float*)nullptr);
}

// Round 4
// 787.945 us; speedup vs baseline: 1.0331x; 1.0331x over previous
//
#include <hip/hip_runtime.h>

// StressTestModel: B=4 S=1024 V=32000 D=128 H=8 dh=16 N=128
// Pipeline: prol(cast+prep) -> scan(+xposeT) -> qk -> attn_z -> attn_w(+mirror zero)
//           -> ctx(fused 2-GEMM + X-add) -> theta -> WriWi gemm(+silu) -> out gemm(nt)

#define DEV static __device__ __forceinline__

typedef __attribute__((ext_vector_type(8))) short short8;
typedef __attribute__((ext_vector_type(4))) float f32x4;

#define INV2PI 0.15915494309189535f
#define INVPI  0.3183098861837907f
#define PHI    1.6180339887498949f
#define SQRT2  1.4142135623730951f
#define SS2    0.25503471060f         /* log2(e)/sqrt(32) */

DEV unsigned short f2bf(float x){
  unsigned u = __float_as_uint(x);
  u += 0x7fff + ((u >> 16) & 1);      // RNE
  return (unsigned short)(u >> 16);
}
DEV float fract1(float x){ return __builtin_amdgcn_fractf(x); }
DEV float sin2pi(float f){ return __builtin_amdgcn_sinf(f); }   // v_sin: revolutions
DEV float cos2pi(float f){ return __builtin_amdgcn_cosf(f); }
DEV float rcpf_(float x){ return __builtin_amdgcn_rcpf(x); }

DEV void cp16(const float* g, float* l){
  __builtin_amdgcn_global_load_lds(
      (const __attribute__((address_space(1))) unsigned*)g,
      (__attribute__((address_space(3))) unsigned*)l, 16, 0, 0);
}

// ---------------- prologue: weight casts/transposes + embedding gather/scan coeffs ----
// blocks [0,16256): cast region.  blocks [16256,18304): prep region (2 rows each).
// P[(b*1024+t)*128+d] = (a2, c2):  u' = sin2pi(fract(u*a2 + c2)), s = sqrt2*u'
__global__ __launch_bounds__(256) void k_prol(
    const float* __restrict__ Wctx, const float* __restrict__ Wres,
    const float* __restrict__ Bres, const float* __restrict__ Wreal,
    const float* __restrict__ Wimag, const float* __restrict__ Wout,
    unsigned short* __restrict__ Woutb, unsigned short* __restrict__ Wctxb,
    unsigned short* __restrict__ WriTb, float* __restrict__ raT,
    float* __restrict__ rcT,
    const int* __restrict__ ids, const float* __restrict__ emb,
    float* __restrict__ P){
  int bx = blockIdx.x;
  if (bx < 16256){
    int i = bx * 256 + threadIdx.x;
    if (i < 4096000){ Woutb[i] = f2bf(Wout[i]); return; }
    i -= 4096000;
    if (i < 16384){ Wctxb[i] = f2bf(Wctx[i]); return; }
    i -= 16384;
    if (i < 32768){
      int d = i >> 8, kk = i & 255;
      WriTb[i] = f2bf(kk < 128 ? Wreal[d*128 + kk] : Wimag[d*128 + kk - 128]);
      return;
    }
    i -= 32768;
    int d = i >> 7, n = i & 127;
    raT[i] = INV2PI * rcpf_(1.f + fabsf(Wres[n*128 + d]));  // raT[d][n]
    rcT[i] = Bres[n*128 + d] * INV2PI;                      // rcT[d][n]
    return;
  }
  int bt = (bx - 16256)*2 + (threadIdx.x >> 7);   // b*1024 + t
  int t  = bt & 1023;
  int d  = threadIdx.x & 127;
  int id = ids[bt];
  float w  = emb[id*256 + d];
  float bb = emb[id*256 + 128 + d];
  // sin+cos fold: s = sqrt2*sin2pi(rev + 1/8); fold sqrt2 into a, 1/8 into c
  float a2 = SQRT2 * INV2PI * rcpf_(1.f + fabsf(w));
  float c2 = (bb + (float)t * PHI) * INVPI + 0.125f;
  ((float2*)P)[bt*128 + d] = make_float2(a2, c2);
}

// ---------------- sequential scan: u_t = sin2pi(fract(u_{t-1}*a2 + c2)), s = sqrt2*u ----
// fused: also emits X^T in bf16 (64 B contiguous per thread per chunk)
// NOTE: t-loop MUST be fully unrolled -- partial unroll makes pk[] runtime-indexed
//       -> scratch spill on the serial critical path (R3 regression).
__global__ __launch_bounds__(128) void k_scan(const float* __restrict__ P,
                                              float* __restrict__ X,
                                              unsigned short* __restrict__ XT){
  __shared__ float buf[2][32*256];   // 64 KiB: double-buffered 32-step chunks
  int b  = blockIdx.x;
  int tid = threadIdx.x;
  int wv = tid >> 6, ln = tid & 63;
  const float* Pb = P + (size_t)b * 1024 * 256;
  for (int i = 0; i < 16; i++){
    int o = (i*2 + wv) * 256;
    cp16(Pb + o + ln*4, &buf[0][o]);
  }
  __syncthreads();
  float u = 0.f;   // u = s/sqrt2; first step rev = c2 matches s0=0
  float* Xb = X + (size_t)b * 1024 * 128;
  unsigned short* XTb = XT + (size_t)(b*128 + tid) * 1024;
  for (int c = 0; c < 32; c++){
    int cur = c & 1;
    if (c + 1 < 32){
      const float* Pn = Pb + (size_t)(c+1) * 8192;
      float* lb = &buf[cur ^ 1][0];
      for (int i = 0; i < 16; i++){
        int o = (i*2 + wv) * 256;
        cp16(Pn + o + ln*4, lb + o);
      }
    }
    const float* bc = &buf[cur][0];
    unsigned pk[16];
    #pragma unroll
    for (int t = 0; t < 32; t++){
      float a  = bc[t*256 + tid*2];
      float cc = bc[t*256 + tid*2 + 1];
      float f = fract1(fmaf(u, a, cc));   // chain: fmaf -> fract -> sin
      u = sin2pi(f);
      float s = u * SQRT2;                // off-chain
      Xb[(c*32 + t)*128 + tid] = s;
      unsigned short h = f2bf(s);
      if (t & 1) pk[t>>1] |= (unsigned)h << 16;
      else       pk[t>>1]  = (unsigned)h;
    }
    uint4* dst = (uint4*)(XTb + c*32);
    #pragma unroll
    for (int i = 0; i < 4; i++)
      dst[i] = make_uint4(pk[i*4+0], pk[i*4+1], pk[i*4+2], pk[i*4+3]);
    __syncthreads();
  }
}

// ---------------- q/k build: q[b][t][h][0..15]=cos, [16..31]=sin ----------------
__global__ __launch_bounds__(128) void k_qk(const float* __restrict__ X,
    const float* __restrict__ wq, const float* __restrict__ bq,
    const float* __restrict__ wk, const float* __restrict__ bk,
    unsigned short* __restrict__ q, unsigned short* __restrict__ k){
  int bt = blockIdx.x;
  int t = bt & 1023;
  int tid = threadIdx.x;            // h*16 + c
  float x = X[(size_t)bt*128 + tid];
  int h = tid >> 4, c = tid & 15;
  size_t base = (size_t)bt*256 + h*32 + c;
  float aq = rcpf_(1.f + fabsf(wq[tid]));
  float fq = fract1(fmaf(x, aq, bq[tid] + (float)t * PHI) * INV2PI);
  q[base]      = f2bf(cos2pi(fq));
  q[base + 16] = f2bf(sin2pi(fq));
  float ak = rcpf_(1.f + fabsf(wk[tid]));
  float fk = fract1(fmaf(x, ak, bk[tid]) * INV2PI);
  k[base]      = f2bf(cos2pi(fk));
  k[base + 16] = f2bf(sin2pi(fk));
}

// ---------------- attention pass 1: Z[b][h][i] = sum_{j<i} exp(score) ----------------
// scores bounded by 2.83 -> no max subtraction needed
__global__ __launch_bounds__(256) void k_attn_z(const unsigned short* __restrict__ q,
    const unsigned short* __restrict__ k, float* __restrict__ Z){
  int blk = blockIdx.x;             // b*128 + h*16 + it
  int it = blk & 15, h = (blk >> 4) & 7, b = blk >> 7;
  int tid = threadIdx.x, w = tid >> 6, ln = tid & 63;
  int ib = it*64 + w*16;
  short8 qa = *(const short8*)(q + ((size_t)(b*1024 + ib + (ln & 15))*8 + h)*32 + (ln >> 4)*8);
  const unsigned short* kb = k + ((size_t)(b*1024 + (ln & 15))*8 + h)*32 + (ln >> 4)*8;
  float z0 = 0.f, z1 = 0.f, z2 = 0.f, z3 = 0.f;
  int irow = ib + (ln >> 4)*4;
  int jcol = ln & 15;
  for (int jt = 0; jt <= (ib >> 4); jt++){
    short8 kf = *(const short8*)(kb + (size_t)jt*16*256);
    f32x4 c = {0.f, 0.f, 0.f, 0.f};
    c = __builtin_amdgcn_mfma_f32_16x16x32_bf16(qa, kf, c, 0, 0, 0);
    int j = jt*16 + jcol;
    if (j < irow + 0) z0 += exp2f(c[0]*SS2);
    if (j < irow + 1) z1 += exp2f(c[1]*SS2);
    if (j < irow + 2) z2 += exp2f(c[2]*SS2);
    if (j < irow + 3) z3 += exp2f(c[3]*SS2);
  }
  #pragma unroll
  for (int m = 1; m < 16; m <<= 1){
    z0 += __shfl_xor(z0, m, 64); z1 += __shfl_xor(z1, m, 64);
    z2 += __shfl_xor(z2, m, 64); z3 += __shfl_xor(z3, m, 64);
  }
  if ((ln & 15) == 0){
    float* zp = Z + (size_t)(b*8 + h)*1024 + irow;
    zp[0] = z0; zp[1] = z1; zp[2] = z2; zp[3] = z3;
  }
}

// ---------------- attention pass 2: Wsum[b][i][j] = sum_h exp(score)/Z ----------------
// off-diagonal blocks also zero their mirrored upper-triangle tile (replaces memset)
__global__ __launch_bounds__(256) void k_attn_w(const unsigned short* __restrict__ q,
    const unsigned short* __restrict__ k, const float* __restrict__ Z,
    unsigned short* __restrict__ W){
  __shared__ float invZ[8][64];
  int b = blockIdx.x / 136, tr = blockIdx.x % 136;
  int it = 0; while ((it+1)*(it+2)/2 <= tr) it++;
  int jt = tr - it*(it+1)/2;
  int ib = it*64, jb = jt*64;
  int tid = threadIdx.x;
  if (it != jt){
    // zero mirrored tile: rows [jb,jb+64) cols [ib,ib+64)  (strictly upper)
    uint4 z4 = make_uint4(0u, 0u, 0u, 0u);
    int idx = tid*2;
    #pragma unroll
    for (int s = 0; s < 2; s++, idx++){
      int row = idx >> 3, c4 = idx & 7;
      *(uint4*)(W + (size_t)(b*1024 + jb + row)*1024 + ib + c4*8) = z4;
    }
  }
  for (int i = tid; i < 512; i += 256){
    int hh = i >> 6, rr = i & 63;
    float zz = Z[(size_t)(b*8 + hh)*1024 + ib + rr];
    invZ[hh][rr] = zz > 0.f ? rcpf_(zz) : 0.f;
  }
  __syncthreads();
  int w = tid >> 6, ln = tid & 63;
  int iw = ib + w*16;
  int rloc = w*16 + (ln >> 4)*4;
  int irow = iw + (ln >> 4)*4;
  int jcol = ln & 15;
  float acc[4][4] = {};
  for (int h = 0; h < 8; h++){
    short8 qa = *(const short8*)(q + ((size_t)(b*1024 + iw + (ln & 15))*8 + h)*32 + (ln >> 4)*8);
    float iz0 = invZ[h][rloc+0], iz1 = invZ[h][rloc+1];
    float iz2 = invZ[h][rloc+2], iz3 = invZ[h][rloc+3];
    for (int jtt = 0; jtt < 4; jtt++){
      short8 kf = *(const short8*)(k + ((size_t)(b*1024 + jb + jtt*16 + (ln & 15))*8 + h)*32 + (ln >> 4)*8);
      f32x4 c = {0.f, 0.f, 0.f, 0.f};
      c = __builtin_amdgcn_mfma_f32_16x16x32_bf16(qa, kf, c, 0, 0, 0);
      int j = jb + jtt*16 + jcol;
      if (j < irow + 0) acc[jtt][0] += exp2f(c[0]*SS2)*iz0;
      if (j < irow + 1) acc[jtt][1] += exp2f(c[1]*SS2)*iz1;
      if (j < irow + 2) acc[jtt][2] += exp2f(c[2]*SS2)*iz2;
      if (j < irow + 3) acc[jtt][3] += exp2f(c[3]*SS2)*iz3;
    }
  }
  #pragma unroll
  for (int jtt = 0; jtt < 4; jtt++)
    #pragma unroll
    for (int r = 0; r < 4; r++)
      W[(size_t)(b*1024 + irow + r)*1024 + jb + jtt*16 + jcol] = f2bf(acc[jtt][r]);
}

// ---------------- fused: tmp = Wsum@X (causal), xout = X + bf16(tmp)@Wctx^T -------
// grid (8,1,4); each block owns a complete 128x128 tmp tile (N=128), routes it
// through LDS (stride 136 -> 16B-aligned b128 reads), then K=128 second GEMM.
__global__ __launch_bounds__(256) void k_ctx(const unsigned short* __restrict__ Wsum,
    const unsigned short* __restrict__ XT, const unsigned short* __restrict__ Wctxb,
    const float* __restrict__ X, float* __restrict__ xout){
  __shared__ unsigned short tile[128][136];
  int b = blockIdx.z;
  const unsigned short* A = Wsum + (long)b*1024*1024;
  const unsigned short* Bm = XT + (long)b*128*1024;
  int tid = threadIdx.x, w = tid >> 6, ln = tid & 63;
  int mq = (w & 1)*64, nq = (w >> 1)*64;
  int m0 = blockIdx.x*128 + mq;
  int kmax = (blockIdx.x + 1)*128;
  f32x4 acc[4][4];
  #pragma unroll
  for (int i = 0; i < 4; i++)
    #pragma unroll
    for (int j = 0; j < 4; j++) acc[i][j] = (f32x4){0.f, 0.f, 0.f, 0.f};
  const unsigned short* Ap = A + (long)(m0 + (ln & 15))*1024 + (ln >> 4)*8;
  const unsigned short* Bp = Bm + (long)(nq + (ln & 15))*1024 + (ln >> 4)*8;
  for (int kb = 0; kb < kmax; kb += 32){
    short8 af[4], bf[4];
    #pragma unroll
    for (int i = 0; i < 4; i++) af[i] = *(const short8*)(Ap + (long)i*16*1024 + kb);
    #pragma unroll
    for (int i = 0; i < 4; i++) bf[i] = *(const short8*)(Bp + (long)i*16*1024 + kb);
    #pragma unroll
    for (int i = 0; i < 4; i++)
      #pragma unroll
      for (int j = 0; j < 4; j++)
        acc[i][j] = __builtin_amdgcn_mfma_f32_16x16x32_bf16(af[i], bf[j], acc[i][j], 0, 0, 0);
  }
  int r0 = (ln >> 4)*4, jc = ln & 15;
  #pragma unroll
  for (int i = 0; i < 4; i++)
    #pragma unroll
    for (int j = 0; j < 4; j++)
      #pragma unroll
      for (int r = 0; r < 4; r++)
        tile[mq + i*16 + r0 + r][nq + j*16 + jc] = f2bf(acc[i][j][r]);
  __syncthreads();
  // phase 2: quadrant (mq, nq) of tile_bf16 @ Wctxb^T, K=128
  f32x4 acc2[4][4];
  #pragma unroll
  for (int i = 0; i < 4; i++)
    #pragma unroll
    for (int j = 0; j < 4; j++) acc2[i][j] = (f32x4){0.f, 0.f, 0.f, 0.f};
  for (int kb = 0; kb < 128; kb += 32){
    short8 af[4], bf[4];
    #pragma unroll
    for (int i = 0; i < 4; i++)
      af[i] = *(const short8*)&tile[mq + i*16 + (ln & 15)][(ln >> 4)*8 + kb];
    #pragma unroll
    for (int j = 0; j < 4; j++)
      bf[j] = *(const short8*)(Wctxb + (long)(nq + j*16 + (ln & 15))*128 + (ln >> 4)*8 + kb);
    #pragma unroll
    for (int i = 0; i < 4; i++)
      #pragma unroll
      for (int j = 0; j < 4; j++)
        acc2[i][j] = __builtin_amdgcn_mfma_f32_16x16x32_bf16(af[i], bf[j], acc2[i][j], 0, 0, 0);
  }
  // epilogue: xout = X + ctx2  (absorbs k_theta's add)
  #pragma unroll
  for (int i = 0; i < 4; i++)
    #pragma unroll
    for (int j = 0; j < 4; j++)
      #pragma unroll
      for (int r = 0; r < 4; r++){
        long idx = (long)(b*1024 + blockIdx.x*128 + mq + i*16 + r0 + r)*128 + nq + j*16 + jc;
        xout[idx] = X[idx] + acc2[i][j][r];
      }
}

// ---------------- cs/ss = sum_d cos/sin(theta), from xout ----------------
__global__ __launch_bounds__(128) void k_theta(const float* __restrict__ xout,
    const float* __restrict__ raT, const float* __restrict__ rcT,
    unsigned short* __restrict__ A7){
  __shared__ float xs[8][128];
  int b = blockIdx.x >> 7, sc = blockIdx.x & 127;
  int s0 = sc*8;
  int n = threadIdx.x;
  #pragma unroll
  for (int s = 0; s < 8; s++){
    size_t idx = (size_t)(b*1024 + s0 + s)*128 + n;
    xs[s][n] = xout[idx];
  }
  __syncthreads();
  float tp[8];
  #pragma unroll
  for (int s = 0; s < 8; s++) tp[s] = (float)(s0 + s) * (float)(PHI * INV2PI);
  float cs[8] = {0,0,0,0,0,0,0,0}, ss[8] = {0,0,0,0,0,0,0,0};
  for (int d = 0; d < 128; d++){
    float a  = raT[d*128 + n];
    float c0 = rcT[d*128 + n];
    #pragma unroll
    for (int s = 0; s < 8; s++){
      float f = fract1(fmaf(xs[s][d], a, c0) + tp[s]);
      cs[s] += cos2pi(f);
      ss[s] += sin2pi(f);
    }
  }
  #pragma unroll
  for (int s = 0; s < 8; s++){
    size_t row = (size_t)(b*1024 + s0 + s);
    A7[row*256 + n]       = f2bf(cs[s]);
    A7[row*256 + 128 + n] = f2bf(ss[s]);
  }
}

// ---------------- generic bf16 MFMA GEMM: C[m][n] = sum_k A[m][k]*B[n][k] ----------------
// obf: 0 = f32 store, 1 = bf16 store, 2 = bf16(Xadd + silu(acc)), 3 = f32 nontemporal
__global__ __launch_bounds__(256) void k_gemm(const unsigned short* __restrict__ A,
    const unsigned short* __restrict__ B, void* __restrict__ Cv,
    int K, int lda, int ldb, int ldc,
    long Abat, long Bbat, long Cbat, int causal, int obf,
    const float* __restrict__ Xadd){
  int bz = blockIdx.z;
  A += (long)bz * Abat; B += (long)bz * Bbat;
  int tid = threadIdx.x, w = tid >> 6, ln = tid & 63;
  int m0 = blockIdx.x*128 + (w & 1)*64;
  int n0 = blockIdx.y*128 + (w >> 1)*64;
  int kmax = causal ? (blockIdx.x + 1)*128 : K;
  if (kmax > K) kmax = K;
  f32x4 acc[4][4];
  #pragma unroll
  for (int i = 0; i < 4; i++)
    #pragma unroll
    for (int j = 0; j < 4; j++) acc[i][j] = (f32x4){0.f, 0.f, 0.f, 0.f};
  const unsigned short* Ap = A + (long)(m0 + (ln & 15))*lda + (ln >> 4)*8;
  const unsigned short* Bp = B + (long)(n0 + (ln & 15))*ldb + (ln >> 4)*8;
  for (int kb = 0; kb < kmax; kb += 32){
    short8 af[4], bf[4];
    #pragma unroll
    for (int i = 0; i < 4; i++) af[i] = *(const short8*)(Ap + (long)i*16*lda + kb);
    #pragma unroll
    for (int i = 0; i < 4; i++) bf[i] = *(const short8*)(Bp + (long)i*16*ldb + kb);
    #pragma unroll
    for (int i = 0; i < 4; i++)
      #pragma unroll
      for (int j = 0; j < 4; j++)
        acc[i][j] = __builtin_amdgcn_mfma_f32_16x16x32_bf16(af[i], bf[j], acc[i][j], 0, 0, 0);
  }
  int r0 = (ln >> 4)*4, jc = ln & 15;
  if (obf == 1){
    unsigned short* C = (unsigned short*)Cv + (long)bz * Cbat;
    #pragma unroll
    for (int i = 0; i < 4; i++)
      #pragma unroll
      for (int j = 0; j < 4; j++)
        #pragma unroll
        for (int r = 0; r < 4; r++)
          C[(long)(m0 + i*16 + r0 + r)*ldc + n0 + j*16 + jc] = f2bf(acc[i][j][r]);
  } else if (obf == 2){
    // epilogue-fused silu: C = bf16(Xadd + acc*sigmoid(acc))
    unsigned short* C = (unsigned short*)Cv;
    #pragma unroll
    for (int i = 0; i < 4; i++)
      #pragma unroll
      for (int j = 0; j < 4; j++)
        #pragma unroll
        for (int r = 0; r < 4; r++){
          long idx = (long)(m0 + i*16 + r0 + r)*ldc + n0 + j*16 + jc;
          float uu = acc[i][j][r];
          float sig = rcpf_(1.f + __expf(-uu));
          C[idx] = f2bf(Xadd[idx] + uu*sig);
        }
  } else if (obf == 3){
    // streaming f32 output (the 524 MB tail) -- keep it out of L2
    float* C = (float*)Cv + (long)bz * Cbat;
    #pragma unroll
    for (int i = 0; i < 4; i++)
      #pragma unroll
      for (int j = 0; j < 4; j++)
        #pragma unroll
        for (int r = 0; r < 4; r++)
          __builtin_nontemporal_store(acc[i][j][r],
              C + (long)(m0 + i*16 + r0 + r)*ldc + n0 + j*16 + jc);
  } else {
    float* C = (float*)Cv + (long)bz * Cbat;
    #pragma unroll
    for (int i = 0; i < 4; i++)
      #pragma unroll
      for (int j = 0; j < 4; j++)
        #pragma unroll
        for (int r = 0; r < 4; r++)
          C[(long)(m0 + i*16 + r0 + r)*ldc + n0 + j*16 + jc] = acc[i][j][r];
  }
}

extern "C" void kernel_launch(void* const* d_in, const int* in_sizes, int n_in,
                              void* d_out, int out_size, void* d_ws, size_t ws_size,
                              hipStream_t stream){
  const int*   ids  = (const int*)  d_in[0];
  const float* emb  = (const float*)d_in[1];
  const float* wq   = (const float*)d_in[2];
  const float* bq   = (const float*)d_in[3];
  const float* wk   = (const float*)d_in[4];
  const float* bk   = (const float*)d_in[5];
  const float* Wctx = (const float*)d_in[6];
  const float* Wres = (const float*)d_in[7];
  const float* Bres = (const float*)d_in[8];
  const float* Wreal= (const float*)d_in[9];
  const float* Wimag= (const float*)d_in[10];
  const float* Wout = (const float*)d_in[11];

  char* p = (char*)d_ws;
  auto alloc = [&](size_t bytes) -> void* {
    void* r = (void*)p; p += (bytes + 255) & ~(size_t)255; return r;
  };
  float*          P     = (float*)         alloc(4ull*1024*128*2*4); // (a2,c2) pairs
  float*          X     = (float*)         alloc(4ull*1024*128*4);
  unsigned short* XT    = (unsigned short*)alloc(4ull*128*1024*2);
  unsigned short* q     = (unsigned short*)alloc(4ull*1024*256*2);
  unsigned short* k     = (unsigned short*)alloc(4ull*1024*256*2);
  float*          Z     = (float*)         alloc(4ull*8*1024*4);
  unsigned short* Wsum  = (unsigned short*)alloc(4ull*1024*1024*2);
  float*          xout  = (float*)         alloc(4ull*1024*128*4);
  unsigned short* A7    = (unsigned short*)alloc(4096ull*256*2);
  unsigned short* xb    = (unsigned short*)alloc(4096ull*128*2);
  unsigned short* Woutb = (unsigned short*)alloc(32000ull*128*2);
  unsigned short* Wctxb = (unsigned short*)alloc(128ull*128*2);
  unsigned short* WriTb = (unsigned short*)alloc(128ull*256*2);
  float*          raT   = (float*)         alloc(16384ull*4);
  float*          rcT   = (float*)         alloc(16384ull*4);

  hipLaunchKernelGGL(k_prol,  dim3(18304), dim3(256), 0, stream,
                     Wctx, Wres, Bres, Wreal, Wimag, Wout, Woutb, Wctxb, WriTb, raT, rcT,
                     ids, emb, P);
  hipLaunchKernelGGL(k_scan,  dim3(4),    dim3(128), 0, stream, P, X, XT);
  hipLaunchKernelGGL(k_qk,    dim3(4096), dim3(128), 0, stream, X, wq, bq, wk, bk, q, k);
  hipLaunchKernelGGL(k_attn_z,dim3(512),  dim3(256), 0, stream, q, k, Z);
  hipLaunchKernelGGL(k_attn_w,dim3(544),  dim3(256), 0, stream, q, k, Z, Wsum);
  // xout = X + (bf16(Wsum@X) @ Wctx^T)   (two GEMMs fused through LDS)
  hipLaunchKernelGGL(k_ctx,   dim3(8,1,4), dim3(256), 0, stream,
                     Wsum, XT, Wctxb, X, xout);
  hipLaunchKernelGGL(k_theta, dim3(512), dim3(128), 0, stream, xout, raT, rcT, A7);
  // xb = bf16(xout + silu([cs|ss] @ [Wr|Wi]^T))   (silu fused into epilogue)
  hipLaunchKernelGGL(k_gemm,  dim3(32,1,1), dim3(256), 0, stream,
                     A7, WriTb, (void*)xb, 256, 256, 256, 128,
                     0L, 0L, 0L, 0, 2, xout);
  // out = x @ Wout^T  (4096 x 32000 x 128) -- the HBM-write-bound tail, nt stores
  hipLaunchKernelGGL(k_gemm,  dim3(32,250,1), dim3(256), 0, stream,
                     xb, Woutb, d_out, 128, 128, 128, 32000,
                     0L, 0L, 0L, 0, 3, (const float*)nullptr);
}